// Round 14
// baseline (428.060 us; speedup 1.0000x reference)
//
#include <hip/hip_runtime.h>
#include <math.h>

#define NUM_CLASSES 81
#define BATCH 64
#define P 8732
#define M 24
#define THRESH 0.5f
#define R_TOTAL (BATCH * P)          // 558848
#define PPB_A 1024                   // priors per block in match kernel
#define NBLK_A 9                     // ceil(P / PPB_A)
#define NBLK_MATCH (NBLK_A * BATCH)  // 576
#define RPB2 256                     // rows per block in stream+topk kernel
#define NBLK_S (R_TOTAL / RPB2)      // 2183

__device__ __forceinline__ float sl1f(float d) {
    float a = fabsf(d);
    return a < 1.f ? 0.5f * a * a : a - 0.5f;
}

__device__ __forceinline__ unsigned long long packkey(float v, int p) {
    return ((unsigned long long)__float_as_uint(v) << 32)
         | (unsigned long long)(0xFFFFFFFFu - (unsigned)p);
}

// ---------- Kernel 1: match (blocks 0..575) + counter-zero block (block 576) ----------
__global__ __launch_bounds__(256) void match_kernel(
    const float* __restrict__ priors,
    const float* __restrict__ truths,
    const int*   __restrict__ labels,
    unsigned short* __restrict__ cmb,
    unsigned long long* __restrict__ bpk_part,
    unsigned* __restrict__ ctrs)          // row_done[64] + done_ctr
{
    const int tid = threadIdx.x;
    if (blockIdx.x == NBLK_MATCH) {
        if (tid < BATCH + 1) ctrs[tid] = 0u;
        return;
    }

    const int b    = blockIdx.x / NBLK_A;
    const int blk  = blockIdx.x - b * NBLK_A;
    const int base = blk * PPB_A;
    const int wid  = tid >> 6;

    __shared__ float s_truth[M][4];
    __shared__ float s_area[M];
    __shared__ int   s_label[M];
    __shared__ float s_v[4][M];
    __shared__ int   s_ix[4][M];

    if (tid < M * 4) ((float*)s_truth)[tid] = truths[b * M * 4 + tid];
    if (tid < M)     s_label[tid] = labels[b * M + tid];
    __syncthreads();
    if (tid < M)
        s_area[tid] = (s_truth[tid][2] - s_truth[tid][0]) * (s_truth[tid][3] - s_truth[tid][1]);
    __syncthreads();

    float bx0[4], by0[4], bx1[4], by1[4], ab[4];
    bool  val[4];
#pragma unroll
    for (int j = 0; j < 4; ++j) {
        int p = base + tid + j * 256;
        val[j] = (p < P);
        float4 pr = ((const float4*)priors)[val[j] ? p : 0];
        bx0[j] = pr.x - pr.z * 0.5f; by0[j] = pr.y - pr.w * 0.5f;
        bx1[j] = pr.x + pr.z * 0.5f; by1[j] = pr.y + pr.w * 0.5f;
        ab[j]  = (bx1[j] - bx0[j]) * (by1[j] - by0[j]);
    }
    float bestv[4] = {-1.f, -1.f, -1.f, -1.f};
    int   bestm[4] = {0, 0, 0, 0};

    for (int m = 0; m < M; ++m) {
        const float tx0 = s_truth[m][0], ty0 = s_truth[m][1];
        const float tx1 = s_truth[m][2], ty1 = s_truth[m][3];
        const float ta  = s_area[m];
        float vmax = -1.f; int ixm = 0x7FFFFFFF;
#pragma unroll
        for (int j = 0; j < 4; ++j) {
            float lx = fmaxf(tx0, bx0[j]);
            float ly = fmaxf(ty0, by0[j]);
            float rx = fminf(tx1, bx1[j]);
            float ry = fminf(ty1, by1[j]);
            float w = fmaxf(rx - lx, 0.f), h = fmaxf(ry - ly, 0.f);
            float inter = w * h;
            float iou = inter / (ta + ab[j] - inter);
            if (!val[j]) iou = -1.f;
            if (iou > bestv[j]) { bestv[j] = iou; bestm[j] = m; }       // first m wins ties
            if (iou > vmax) { vmax = iou; ixm = base + tid + j * 256; } // smaller p wins
        }
        float v = vmax; int ix = ixm;
#pragma unroll
        for (int off = 32; off; off >>= 1) {
            float vo = __shfl_xor(v, off);
            int   io = __shfl_xor(ix, off);
            if (vo > v || (vo == v && io < ix)) { v = vo; ix = io; }
        }
        if ((tid & 63) == 0) { s_v[wid][m] = v; s_ix[wid][m] = ix; }
    }
    __syncthreads();
    if (tid < M) {
        float v = s_v[0][tid]; int ix = s_ix[0][tid];
#pragma unroll
        for (int w = 1; w < 4; ++w) {
            float vo = s_v[w][tid]; int io = s_ix[w][tid];
            if (vo > v || (vo == v && io < ix)) { v = vo; ix = io; }
        }
        bpk_part[((size_t)b * NBLK_A + blk) * M + tid] =
            (v >= 0.f) ? packkey(v, ix) : 0ull;
    }
#pragma unroll
    for (int j = 0; j < 4; ++j) {
        if (val[j]) {
            int p = base + tid + j * 256;
            int conf = (bestv[j] < THRESH) ? 0 : (s_label[bestm[j]] + 1);
            cmb[(size_t)b * P + p] = (unsigned short)(conf | (bestm[j] << 8));
        }
    }
}

// ---------- Kernel 2: stream-LSE + per-batch wait-free topk trigger ----------
__global__ __launch_bounds__(1024) void stream_topk_kernel(
    const float* __restrict__ conf_data,
    const float* __restrict__ loc_data,
    const float* __restrict__ priors,
    const float* __restrict__ truths,
    const int*   __restrict__ labels,
    const unsigned short* __restrict__ cmb,
    const unsigned long long* __restrict__ bpk_part,
    float*  __restrict__ loss_rank,
    double* __restrict__ loss_l_out,
    double* __restrict__ loss_c_out,
    int*    __restrict__ num_pos_out,
    unsigned* __restrict__ ctrs,           // row_done[64] + done_ctr at [64]
    float* __restrict__ out)
{
    const int tid = threadIdx.x;
    const int NT  = 1024;
    const int NW  = NT / 64;
    const int lane = tid & 63;
    const int wid  = tid >> 6;

    // ---------- stream phase: 256 rows, LDS-free, quad-per-row ----------
    {
        const int sbase = blockIdx.x * RPB2;
        const int q = tid >> 2;
        const int l = tid & 3;
        const int r = sbase + q;
        const float* x = conf_data + (size_t)r * NUM_CLASSES;
        float4 v0 = *(const float4*)(x + 0 * 16 + l * 4);
        float4 v1 = *(const float4*)(x + 1 * 16 + l * 4);
        float4 v2 = *(const float4*)(x + 2 * 16 + l * 4);
        float4 v3 = *(const float4*)(x + 3 * 16 + l * 4);
        float4 v4 = *(const float4*)(x + 4 * 16 + l * 4);
        float x80 = x[80];
        float s0 = __expf(v0.x) + __expf(v0.y) + __expf(v0.z) + __expf(v0.w);
        float s1 = __expf(v1.x) + __expf(v1.y) + __expf(v1.z) + __expf(v1.w);
        float s2 = __expf(v2.x) + __expf(v2.y) + __expf(v2.z) + __expf(v2.w);
        float s3 = __expf(v3.x) + __expf(v3.y) + __expf(v3.z) + __expf(v3.w);
        float s4 = __expf(v4.x) + __expf(v4.y) + __expf(v4.z) + __expf(v4.w);
        float s = (s0 + s1) + (s2 + s3) + s4;
        s += __shfl_xor(s, 1);
        s += __shfl_xor(s, 2);
        if (l == 0)
            loss_rank[r] = __logf(s + __expf(x80)) - v0.x;
    }
    __syncthreads();     // all block stores complete (vmcnt drained)

    // ---------- completion accounting (wait-free) ----------
    __shared__ int s_trig[2];
    __shared__ int s_ntrig;
    if (tid == 0) {
        __threadfence();   // release our stores device-wide
        int nt = 0;
        const int sbase = blockIdx.x * RPB2;
        const int b0 = sbase / P;
        const int b1 = (sbase + RPB2 - 1) / P;
        int cnt0 = (b1 > b0) ? ((b0 + 1) * P - sbase) : RPB2;
        unsigned old0 = atomicAdd(&ctrs[b0], (unsigned)cnt0);
        if ((int)old0 + cnt0 == P) s_trig[nt++] = b0;
        if (b1 > b0) {
            int cnt1 = RPB2 - cnt0;
            unsigned old1 = atomicAdd(&ctrs[b1], (unsigned)cnt1);
            if ((int)old1 + cnt1 == P) s_trig[nt++] = b1;
        }
        s_ntrig = nt;
    }
    __syncthreads();
    const int ntrig = s_ntrig;
    if (ntrig == 0) return;
    __threadfence();   // acquire: other blocks' loss_rank now visible

    // ---------- topk phase (runs for 1 or 2 completed batches) ----------
    __shared__ unsigned int s_key[P];
    __shared__ unsigned int s_hist[256];
    __shared__ unsigned int s_suf[256];
    __shared__ unsigned int s_wtot[4];
    __shared__ unsigned int s_prefix;
    __shared__ int s_rem;
    __shared__ double s_dl[NW], s_dc[NW];
    __shared__ int    s_in[NW];
    __shared__ int    s_npt;
    __shared__ double s_llt, s_cet;
    __shared__ int      s_fp[M];
    __shared__ unsigned s_fcm[M];
    __shared__ unsigned s_bit[(P + 31) / 32];
    __shared__ int s_last;

    for (int t = 0; t < ntrig; ++t) {
        const int b = s_trig[t];

        if (tid < (P + 31) / 32) s_bit[tid] = 0u;
        __syncthreads();
        if (tid < M) {
            unsigned long long best = 0ull;
            const unsigned long long* part = bpk_part + (size_t)b * NBLK_A * M + tid;
#pragma unroll
            for (int blk = 0; blk < NBLK_A; ++blk) {
                unsigned long long v = part[(size_t)blk * M];
                if (v > best) best = v;
            }
            int fp = (int)(0xFFFFFFFFu - (unsigned)(best & 0xFFFFFFFFull));
            s_fp[tid]  = fp;
            s_fcm[tid] = (unsigned)((labels[b * M + tid] + 1) | (tid << 8));
            atomicOr(&s_bit[fp >> 5], 1u << (fp & 31));
        }
        __syncthreads();

        double ll = 0.0, ce = 0.0;
        int np = 0;
        for (int p = tid; p < P; p += NT) {
            const int r = b * P + p;
            unsigned cm = cmb[r];
            if ((s_bit[p >> 5] >> (p & 31)) & 1u) {
                for (int mm = 0; mm < M; ++mm)
                    if (p == s_fp[mm]) cm = s_fcm[mm];
            }
            int conf = cm & 0xFF;
            float lr = loss_rank[r];
            unsigned key = __float_as_uint(lr);
            if (conf > 0) {
                key = 0u;
                const float* x = conf_data + (size_t)r * NUM_CLASSES;
                ce += (double)(lr + x[0] - x[conf]);
                ++np;
                int mt = (cm >> 8) & 0xFF;
                float4 tt = ((const float4*)truths)[b * M + mt];
                float4 pr = ((const float4*)priors)[p];
                float4 ld = ((const float4*)loc_data)[r];
                float gcx = ((tt.x + tt.z) * 0.5f - pr.x) / (0.1f * pr.z);
                float gcy = ((tt.y + tt.w) * 0.5f - pr.y) / (0.1f * pr.w);
                float gw  = logf((tt.z - tt.x) / pr.z) / 0.2f;
                float gh  = logf((tt.w - tt.y) / pr.w) / 0.2f;
                ll += (double)(sl1f(ld.x - gcx) + sl1f(ld.y - gcy)
                             + sl1f(ld.z - gw) + sl1f(ld.w - gh));
            }
            s_key[p] = key;
        }
#pragma unroll
        for (int off = 32; off; off >>= 1) {
            ll += __shfl_xor(ll, off);
            ce += __shfl_xor(ce, off);
            np += __shfl_xor(np, off);
        }
        if (lane == 0) { s_dl[wid] = ll; s_dc[wid] = ce; s_in[wid] = np; }
        __syncthreads();
        if (tid == 0) {
            double tl = 0.0, tc = 0.0; int tn = 0;
            for (int w = 0; w < NW; ++w) { tl += s_dl[w]; tc += s_dc[w]; tn += s_in[w]; }
            s_llt = tl; s_cet = tc; s_npt = tn;
        }
        __syncthreads();
        const int np_total = s_npt;
        int k = np_total * 3;
        if (k > P - 1) k = P - 1;

        unsigned int prefix = 0;
        if (k > 0) {
            int rem = k;
            for (int byte = 3; byte >= 0; --byte) {
                if (tid < 256) s_hist[tid] = 0;
                __syncthreads();
                if (byte == 3) {
                    const int PADP = ((P + NT - 1) / NT) * NT;
                    for (int p = tid; p < PADP; p += NT) {
                        bool act = (p < P);
                        unsigned bkt = act ? (s_key[p] >> 24) : 0u;
                        unsigned long long mask = __ballot(act);
                        while (mask) {
                            int leader = __ffsll(mask) - 1;
                            unsigned lb = __shfl(bkt, leader);
                            unsigned long long same = __ballot(act && bkt == lb);
                            if (lane == leader)
                                atomicAdd(&s_hist[lb], (unsigned)__popcll(same));
                            mask &= ~same;
                        }
                    }
                } else {
                    unsigned int himask = 0xFFFFFFFFu << ((byte + 1) * 8);
                    for (int p = tid; p < P; p += NT) {
                        unsigned int key = s_key[p];
                        if ((key & himask) == prefix)
                            atomicAdd(&s_hist[(key >> (byte * 8)) & 255u], 1u);
                    }
                }
                __syncthreads();
                if (tid < 256) {
                    unsigned x = s_hist[tid];
#pragma unroll
                    for (int off = 1; off < 64; off <<= 1) {
                        unsigned y = __shfl_down(x, off);
                        if ((tid & 63) + off < 64) x += y;
                    }
                    s_suf[tid] = x;
                    if ((tid & 63) == 0) s_wtot[tid >> 6] = x;
                }
                __syncthreads();
                if (tid < 256) {
                    unsigned above_w = 0;
                    int w = tid >> 6;
                    for (int w2 = w + 1; w2 < 4; ++w2) above_w += s_wtot[w2];
                    unsigned h     = s_hist[tid];
                    unsigned incl  = s_suf[tid] + above_w;
                    unsigned above = incl - h;
                    if ((int)above < rem && rem <= (int)incl) {
                        s_prefix = prefix | ((unsigned)tid << (byte * 8));
                        s_rem = rem - (int)above;
                    }
                }
                __syncthreads();
                prefix = s_prefix;
                rem    = s_rem;
            }
        }

        double sum_gt = 0.0;
        int    cnt_gt = 0;
        if (k > 0) {
            for (int p = tid; p < P; p += NT) {
                unsigned int key = s_key[p];
                if (key > prefix) { sum_gt += (double)__uint_as_float(key); ++cnt_gt; }
            }
        }
#pragma unroll
        for (int off = 32; off; off >>= 1) {
            sum_gt += __shfl_xor(sum_gt, off);
            cnt_gt += __shfl_xor(cnt_gt, off);
        }
        if (lane == 0) { s_dl[wid] = sum_gt; s_in[wid] = cnt_gt; }
        __syncthreads();
        if (tid == 0) {
            double sg = 0.0; int cg = 0;
            for (int w = 0; w < NW; ++w) { sg += s_dl[w]; cg += s_in[w]; }
            double tk = 0.0;
            if (k > 0) tk = sg + (double)(k - cg) * (double)__uint_as_float(prefix);
            loss_l_out[b]  = s_llt;
            loss_c_out[b]  = s_cet + tk;
            num_pos_out[b] = np_total;
            __threadfence();
            unsigned old = atomicAdd(&ctrs[BATCH], 1u);
            s_last = (old == BATCH - 1) ? 1 : 0;
        }
        __syncthreads();

        if (s_last && tid < 64) {
            __threadfence();
            double fll = loss_l_out[tid];
            double flc = loss_c_out[tid];
            int    fn  = num_pos_out[tid];
#pragma unroll
            for (int off = 32; off; off >>= 1) {
                fll += __shfl_xor(fll, off);
                flc += __shfl_xor(flc, off);
                fn  += __shfl_xor(fn, off);
            }
            if (tid == 0) {
                double N = (double)fn;
                out[0] = (float)(fll / N);
                out[1] = (float)(flc / N);
            }
        }
        __syncthreads();
    }
}

extern "C" void kernel_launch(void* const* d_in, const int* in_sizes, int n_in,
                              void* d_out, int out_size, void* d_ws, size_t ws_size,
                              hipStream_t stream)
{
    const float* loc_data  = (const float*)d_in[0];
    const float* conf_data = (const float*)d_in[1];
    const float* priors    = (const float*)d_in[2];
    const float* truths    = (const float*)d_in[3];
    const int*   labels    = (const int*)d_in[4];
    float* out = (float*)d_out;

    char* ws = (char*)d_ws;
    size_t off = 0;
    float* loss_rank = (float*)(ws + off);             off += (size_t)R_TOTAL * 4;
    unsigned short* cmb = (unsigned short*)(ws + off); off += (size_t)R_TOTAL * 2;
    off = (off + 15) & ~(size_t)15;
    unsigned long long* bpk_part = (unsigned long long*)(ws + off);
    off += (size_t)BATCH * NBLK_A * M * 8;
    int*    num_pos = (int*)(ws + off);    off += 64 * sizeof(int);
    off = (off + 7) & ~(size_t)7;
    double* loss_l  = (double*)(ws + off); off += 64 * sizeof(double);
    double* loss_c  = (double*)(ws + off); off += 64 * sizeof(double);
    unsigned* ctrs  = (unsigned*)(ws + off); off += (BATCH + 1) * sizeof(unsigned);

    match_kernel<<<NBLK_MATCH + 1, 256, 0, stream>>>(priors, truths, labels,
                                                     cmb, bpk_part, ctrs);
    stream_topk_kernel<<<NBLK_S, 1024, 0, stream>>>(conf_data, loc_data, priors,
                                                    truths, labels, cmb, bpk_part,
                                                    loss_rank, loss_l, loss_c,
                                                    num_pos, ctrs, out);
}

// Round 15
// 61.985 us; speedup vs baseline: 6.9058x; 6.9058x over previous
//
#include <hip/hip_runtime.h>
#include <math.h>

#define NUM_CLASSES 81
#define BATCH 64
#define P 8732
#define M 24
#define THRESH 0.5f
#define R_TOTAL (BATCH * P)          // 558848
#define PPB_A 1024                   // priors per block in match path
#define NBLK_A 9                     // ceil(P / PPB_A)
#define NBLK_MATCH (NBLK_A * BATCH)  // 576
#define NBLK_STREAM (R_TOTAL / 64)   // 8732

__device__ __forceinline__ float sl1f(float d) {
    float a = fabsf(d);
    return a < 1.f ? 0.5f * a * a : a - 0.5f;
}

__device__ __forceinline__ unsigned long long packkey(float v, int p) {
    return ((unsigned long long)__float_as_uint(v) << 32)
         | (unsigned long long)(0xFFFFFFFFu - (unsigned)p);
}

struct MatchSmem {
    float truth[M][4];
    float area[M];
    int   label[M];
    float v[4][M];
    int   ix[4][M];
};

// ---------- Kernel 1: match blocks (0..575) co-scheduled with stream blocks (576..9307) ----------
__global__ __launch_bounds__(256) void prep_kernel(
    const float* __restrict__ conf_data,  // [B*P, 81]
    const float* __restrict__ priors,     // [P,4] center-size
    const float* __restrict__ truths,     // [B,M,4] corners
    const int*   __restrict__ labels,     // [B,M]
    float* __restrict__ loss_rank,        // [B*P] out: lse - x[0]
    unsigned short* __restrict__ cmb,     // [B,P] conf | (bti<<8)
    unsigned long long* __restrict__ bpk_part, // [B,NBLK_A,M]
    unsigned* __restrict__ done_ctr)      // re-zeroed every call
{
    const int tid = threadIdx.x;
    __shared__ float s_f[64 * NUM_CLASSES];   // 20736 B; overlaid by match path

    if (blockIdx.x >= NBLK_MATCH) {
        // ---------------- stream path: aligned staged LDS, quad-per-row ----------------
        const int sb = blockIdx.x - NBLK_MATCH;
        const size_t gbase = (size_t)sb * (64 * NUM_CLASSES);      // dwords
        const float4* src4 = (const float4*)(conf_data + gbase);   // 16B-aligned
        float4* s4 = (float4*)s_f;
#pragma unroll
        for (int f = tid; f < (64 * NUM_CLASSES) / 4; f += 256)
            s4[f] = src4[f];                    // aligned, coalesced, ds_write_b128
        __syncthreads();

        const int q = tid >> 2;                 // row 0..63
        const int l = tid & 3;                  // quad lane
        const float* srow = s_f + q * NUM_CLASSES;   // dword stride 81 (odd) -> <=2-way banks
        float a0 = 0.f, a1 = 0.f, a2 = 0.f, a3 = 0.f;
#pragma unroll
        for (int j = 0; j < 20; j += 4) {
            a0 += __expf(srow[l * 20 + j]);
            a1 += __expf(srow[l * 20 + j + 1]);
            a2 += __expf(srow[l * 20 + j + 2]);
            a3 += __expf(srow[l * 20 + j + 3]);
        }
        float s = (a0 + a1) + (a2 + a3);
        s += __shfl_xor(s, 1);
        s += __shfl_xor(s, 2);
        if (l == 0)
            loss_rank[sb * 64 + q] = __logf(s + __expf(srow[80])) - srow[0];
        return;
    }

    // ---------------- match path ----------------
    if (blockIdx.x == 0 && tid == 0) atomicExch(done_ctr, 0u);

    MatchSmem* ms = (MatchSmem*)s_f;
    const int b    = blockIdx.x / NBLK_A;
    const int blk  = blockIdx.x - b * NBLK_A;
    const int base = blk * PPB_A;
    const int wid  = tid >> 6;

    if (tid < M * 4) ((float*)ms->truth)[tid] = truths[b * M * 4 + tid];
    if (tid < M)     ms->label[tid] = labels[b * M + tid];
    __syncthreads();
    if (tid < M)
        ms->area[tid] = (ms->truth[tid][2] - ms->truth[tid][0])
                      * (ms->truth[tid][3] - ms->truth[tid][1]);
    __syncthreads();

    float bx0[4], by0[4], bx1[4], by1[4], ab[4];
    bool  val[4];
#pragma unroll
    for (int j = 0; j < 4; ++j) {
        int p = base + tid + j * 256;
        val[j] = (p < P);
        float4 pr = ((const float4*)priors)[val[j] ? p : 0];
        bx0[j] = pr.x - pr.z * 0.5f; by0[j] = pr.y - pr.w * 0.5f;
        bx1[j] = pr.x + pr.z * 0.5f; by1[j] = pr.y + pr.w * 0.5f;
        ab[j]  = (bx1[j] - bx0[j]) * (by1[j] - by0[j]);
    }
    float bestv[4] = {-1.f, -1.f, -1.f, -1.f};
    int   bestm[4] = {0, 0, 0, 0};

    for (int m = 0; m < M; ++m) {
        const float tx0 = ms->truth[m][0], ty0 = ms->truth[m][1];
        const float tx1 = ms->truth[m][2], ty1 = ms->truth[m][3];
        const float ta  = ms->area[m];
        float vmax = -1.f; int ixm = 0x7FFFFFFF;
#pragma unroll
        for (int j = 0; j < 4; ++j) {
            float lx = fmaxf(tx0, bx0[j]);
            float ly = fmaxf(ty0, by0[j]);
            float rx = fminf(tx1, bx1[j]);
            float ry = fminf(ty1, by1[j]);
            float w = fmaxf(rx - lx, 0.f), h = fmaxf(ry - ly, 0.f);
            float inter = w * h;
            float iou = inter / (ta + ab[j] - inter);
            if (!val[j]) iou = -1.f;
            if (iou > bestv[j]) { bestv[j] = iou; bestm[j] = m; }       // first m wins ties
            if (iou > vmax) { vmax = iou; ixm = base + tid + j * 256; } // smaller p wins
        }
        float v = vmax; int ix = ixm;
#pragma unroll
        for (int off = 32; off; off >>= 1) {
            float vo = __shfl_xor(v, off);
            int   io = __shfl_xor(ix, off);
            if (vo > v || (vo == v && io < ix)) { v = vo; ix = io; }
        }
        if ((tid & 63) == 0) { ms->v[wid][m] = v; ms->ix[wid][m] = ix; }
    }
    __syncthreads();
    if (tid < M) {
        float v = ms->v[0][tid]; int ix = ms->ix[0][tid];
#pragma unroll
        for (int w = 1; w < 4; ++w) {
            float vo = ms->v[w][tid]; int io = ms->ix[w][tid];
            if (vo > v || (vo == v && io < ix)) { v = vo; ix = io; }
        }
        bpk_part[((size_t)b * NBLK_A + blk) * M + tid] =
            (v >= 0.f) ? packkey(v, ix) : 0ull;
    }
#pragma unroll
    for (int j = 0; j < 4; ++j) {
        if (val[j]) {
            int p = base + tid + j * 256;
            int conf = (bestv[j] < THRESH) ? 0 : (ms->label[bestm[j]] + 1);
            cmb[(size_t)b * P + p] = (unsigned short)(conf | (bestm[j] << 8));
        }
    }
}

// ---------- Kernel 2: forced merge + fixup + top-k radix select + device-side final ----------
__global__ __launch_bounds__(1024) void topk_kernel(
    const float* __restrict__ loss_rank,   // [B,P]: lse - x[0]
    const unsigned short* __restrict__ cmb,
    const unsigned long long* __restrict__ bpk_part,
    const int*   __restrict__ labels,
    const float* __restrict__ conf_data,
    const float* __restrict__ loc_data,
    const float* __restrict__ priors,
    const float* __restrict__ truths,
    double* __restrict__ loss_l_out,       // [B]
    double* __restrict__ loss_c_out,       // [B]
    int*    __restrict__ num_pos_out,      // [B]
    unsigned* __restrict__ done_ctr,
    float* __restrict__ out)               // [2]
{
    const int b   = blockIdx.x;
    const int tid = threadIdx.x;
    const int NT  = 1024;
    const int NW  = NT / 64;
    const int lane = tid & 63;
    const int wid  = tid >> 6;

    __shared__ unsigned int s_key[P];
    __shared__ unsigned int s_hist[256];
    __shared__ unsigned int s_suf[256];
    __shared__ unsigned int s_wtot[4];
    __shared__ unsigned int s_prefix;
    __shared__ int s_rem;
    __shared__ double s_dl[NW], s_dc[NW];
    __shared__ int    s_in[NW];
    __shared__ int    s_npt;
    __shared__ double s_llt, s_cet;
    __shared__ int      s_fp[M];           // forced prior per truth
    __shared__ unsigned s_fcm[M];          // forced cm per truth
    __shared__ unsigned s_bit[(P + 31) / 32];  // forced-prior bitmap (273 words)
    __shared__ int s_last;

    // ---- merge per-block partials -> forced matches; build bitmap ----
    if (tid < (P + 31) / 32) s_bit[tid] = 0u;
    __syncthreads();
    if (tid < M) {
        unsigned long long best = 0ull;
        const unsigned long long* part = bpk_part + (size_t)b * NBLK_A * M + tid;
#pragma unroll
        for (int blk = 0; blk < NBLK_A; ++blk) {
            unsigned long long v = part[(size_t)blk * M];
            if (v > best) best = v;
        }
        int fp = (int)(0xFFFFFFFFu - (unsigned)(best & 0xFFFFFFFFull));
        s_fp[tid]  = fp;
        s_fcm[tid] = (unsigned)((labels[b * M + tid] + 1) | (tid << 8));
        atomicOr(&s_bit[fp >> 5], 1u << (fp & 31));
    }
    __syncthreads();

    // ---- load + forced patch (bitmap-guarded) + positive fixup ----
    double ll = 0.0, ce = 0.0;
    int np = 0;
    for (int p = tid; p < P; p += NT) {
        const int r = b * P + p;
        unsigned cm = cmb[r];
        if ((s_bit[p >> 5] >> (p & 31)) & 1u) {
            for (int mm = 0; mm < M; ++mm)        // forward scan: last m wins
                if (p == s_fp[mm]) cm = s_fcm[mm];
        }
        int conf = cm & 0xFF;
        float lr = loss_rank[r];
        unsigned key = __float_as_uint(lr);
        if (conf > 0) {
            key = 0u;                                  // positives ranked 0
            const float* x = conf_data + (size_t)r * NUM_CLASSES;
            ce += (double)(lr + x[0] - x[conf]);       // = lse - x[conf]
            ++np;
            int mt = (cm >> 8) & 0xFF;
            float4 t  = ((const float4*)truths)[b * M + mt];
            float4 pr = ((const float4*)priors)[p];
            float4 ld = ((const float4*)loc_data)[r];
            float gcx = ((t.x + t.z) * 0.5f - pr.x) / (0.1f * pr.z);
            float gcy = ((t.y + t.w) * 0.5f - pr.y) / (0.1f * pr.w);
            float gw  = logf((t.z - t.x) / pr.z) / 0.2f;
            float gh  = logf((t.w - t.y) / pr.w) / 0.2f;
            ll += (double)(sl1f(ld.x - gcx) + sl1f(ld.y - gcy)
                         + sl1f(ld.z - gw) + sl1f(ld.w - gh));
        }
        s_key[p] = key;
    }
#pragma unroll
    for (int off = 32; off; off >>= 1) {
        ll += __shfl_xor(ll, off);
        ce += __shfl_xor(ce, off);
        np += __shfl_xor(np, off);
    }
    if (lane == 0) { s_dl[wid] = ll; s_dc[wid] = ce; s_in[wid] = np; }
    __syncthreads();
    if (tid == 0) {
        double tl = 0.0, tc = 0.0; int tn = 0;
        for (int w = 0; w < NW; ++w) { tl += s_dl[w]; tc += s_dc[w]; tn += s_in[w]; }
        s_llt = tl; s_cet = tc; s_npt = tn;
    }
    __syncthreads();
    const int np_total = s_npt;
    int k = np_total * 3;
    if (k > P - 1) k = P - 1;

    // ---- radix select: k-th largest key ----
    unsigned int prefix = 0;
    if (k > 0) {
        int rem = k;
        for (int byte = 3; byte >= 0; --byte) {
            if (tid < 256) s_hist[tid] = 0;
            __syncthreads();
            if (byte == 3) {
                // wave-aggregated histogram (value distribution concentrates exp byte)
                const int PADP = ((P + NT - 1) / NT) * NT;
                for (int p = tid; p < PADP; p += NT) {
                    bool act = (p < P);
                    unsigned bkt = act ? (s_key[p] >> 24) : 0u;
                    unsigned long long mask = __ballot(act);
                    while (mask) {
                        int leader = __ffsll(mask) - 1;
                        unsigned lb = __shfl(bkt, leader);
                        unsigned long long same = __ballot(act && bkt == lb);
                        if (lane == leader)
                            atomicAdd(&s_hist[lb], (unsigned)__popcll(same));
                        mask &= ~same;
                    }
                }
            } else {
                unsigned int himask = 0xFFFFFFFFu << ((byte + 1) * 8);
                for (int p = tid; p < P; p += NT) {
                    unsigned int key = s_key[p];
                    if ((key & himask) == prefix)
                        atomicAdd(&s_hist[(key >> (byte * 8)) & 255u], 1u);
                }
            }
            __syncthreads();
            // parallel suffix sum over 256 buckets (threads 0..255 = waves 0..3)
            if (tid < 256) {
                unsigned x = s_hist[tid];
#pragma unroll
                for (int off = 1; off < 64; off <<= 1) {
                    unsigned y = __shfl_down(x, off);
                    if ((tid & 63) + off < 64) x += y;
                }
                s_suf[tid] = x;
                if ((tid & 63) == 0) s_wtot[tid >> 6] = x;
            }
            __syncthreads();
            if (tid < 256) {
                unsigned above_w = 0;
                int w = tid >> 6;
                for (int w2 = w + 1; w2 < 4; ++w2) above_w += s_wtot[w2];
                unsigned h     = s_hist[tid];
                unsigned incl  = s_suf[tid] + above_w;   // keys in buckets >= tid
                unsigned above = incl - h;               // keys in buckets >  tid
                if ((int)above < rem && rem <= (int)incl) {
                    s_prefix = prefix | ((unsigned)tid << (byte * 8));
                    s_rem = rem - (int)above;
                }
            }
            __syncthreads();
            prefix = s_prefix;
            rem    = s_rem;
        }
    }

    // ---- sum of values > T, plus (k - cnt) copies of T ----
    double sum_gt = 0.0;
    int    cnt_gt = 0;
    if (k > 0) {
        for (int p = tid; p < P; p += NT) {
            unsigned int key = s_key[p];
            if (key > prefix) { sum_gt += (double)__uint_as_float(key); ++cnt_gt; }
        }
    }
#pragma unroll
    for (int off = 32; off; off >>= 1) {
        sum_gt += __shfl_xor(sum_gt, off);
        cnt_gt += __shfl_xor(cnt_gt, off);
    }
    if (lane == 0) { s_dl[wid] = sum_gt; s_in[wid] = cnt_gt; }
    __syncthreads();
    if (tid == 0) {
        double sg = 0.0; int cg = 0;
        for (int w = 0; w < NW; ++w) { sg += s_dl[w]; cg += s_in[w]; }
        double tk = 0.0;
        if (k > 0) tk = sg + (double)(k - cg) * (double)__uint_as_float(prefix);
        loss_l_out[b]  = s_llt;
        loss_c_out[b]  = s_cet + tk;
        num_pos_out[b] = np_total;
        __threadfence();                          // publish results device-wide
        unsigned old = atomicAdd(done_ctr, 1u);
        s_last = (old == BATCH - 1) ? 1 : 0;
    }
    __syncthreads();

    // ---- last block performs the final reduction (rocPRIM-style) ----
    if (s_last && tid < 64) {
        __threadfence();                          // acquire
        double fll = loss_l_out[tid];
        double flc = loss_c_out[tid];
        int    fn  = num_pos_out[tid];
#pragma unroll
        for (int off = 32; off; off >>= 1) {
            fll += __shfl_xor(fll, off);
            flc += __shfl_xor(flc, off);
            fn  += __shfl_xor(fn, off);
        }
        if (tid == 0) {
            double N = (double)fn;
            out[0] = (float)(fll / N);
            out[1] = (float)(flc / N);
        }
    }
}

extern "C" void kernel_launch(void* const* d_in, const int* in_sizes, int n_in,
                              void* d_out, int out_size, void* d_ws, size_t ws_size,
                              hipStream_t stream)
{
    const float* loc_data  = (const float*)d_in[0];
    const float* conf_data = (const float*)d_in[1];
    const float* priors    = (const float*)d_in[2];
    const float* truths    = (const float*)d_in[3];
    const int*   labels    = (const int*)d_in[4];
    float* out = (float*)d_out;

    char* ws = (char*)d_ws;
    size_t off = 0;
    float* loss_rank = (float*)(ws + off);             off += (size_t)R_TOTAL * 4;
    unsigned short* cmb = (unsigned short*)(ws + off); off += (size_t)R_TOTAL * 2;
    off = (off + 15) & ~(size_t)15;
    unsigned long long* bpk_part = (unsigned long long*)(ws + off);
    off += (size_t)BATCH * NBLK_A * M * 8;
    int*    num_pos = (int*)(ws + off);    off += 64 * sizeof(int);
    off = (off + 7) & ~(size_t)7;
    double* loss_l  = (double*)(ws + off); off += 64 * sizeof(double);
    double* loss_c  = (double*)(ws + off); off += 64 * sizeof(double);
    unsigned* done_ctr = (unsigned*)(ws + off); off += sizeof(unsigned);

    prep_kernel<<<NBLK_MATCH + NBLK_STREAM, 256, 0, stream>>>(
        conf_data, priors, truths, labels, loss_rank, cmb, bpk_part, done_ctr);
    topk_kernel<<<BATCH, 1024, 0, stream>>>(loss_rank, cmb, bpk_part, labels,
                                            conf_data, loc_data, priors, truths,
                                            loss_l, loss_c, num_pos, done_ctr, out);
}